// Round 1
// baseline (218.436 us; speedup 1.0000x reference)
//
#include <hip/hip_runtime.h>

#define K 11
#define RAD 5
#define TW 32
#define TH 32
#define HW (TW + 2*RAD)  // 42
#define HH (TH + 2*RAD)  // 42
#define BSIZE 256
#define IMG_H 512
#define IMG_W 512
#define BATCH 64

__global__ __launch_bounds__(BSIZE) void ssim_tile_kernel(
    const float* __restrict__ img1, const float* __restrict__ img2,
    const float* __restrict__ window, float* __restrict__ partials)
{
    __shared__ float sx[HH][HW];
    __shared__ float sy[HH][HW];
    __shared__ float hb1[HH][TW];
    __shared__ float hb2[HH][TW];
    __shared__ float hb11[HH][TW];
    __shared__ float hb22[HH][TW];
    __shared__ float hb12[HH][TW];
    __shared__ float gw[K];
    __shared__ float wsum[4];

    const int tid = threadIdx.x;
    const int b  = blockIdx.z;
    const int y0 = blockIdx.y * TH - RAD;
    const int x0 = blockIdx.x * TW - RAD;

    // 1-D gaussian from row sums of the 2-D window (g sums to 1 so row_sum = g[i])
    if (tid < K) {
        float s = 0.f;
        #pragma unroll
        for (int j = 0; j < K; ++j) s += window[tid * K + j];
        gw[tid] = s;
    }

    const float* p1 = img1 + (size_t)b * IMG_H * IMG_W;
    const float* p2 = img2 + (size_t)b * IMG_H * IMG_W;

    // stage raw tiles with zero-filled halo (SAME zero padding)
    for (int i = tid; i < HH * HW; i += BSIZE) {
        int r = i / HW, c = i % HW;
        int gr = y0 + r, gc = x0 + c;
        bool ok = (gr >= 0) & (gr < IMG_H) & (gc >= 0) & (gc < IMG_W);
        size_t off = (size_t)gr * IMG_W + gc;
        sx[r][c] = ok ? p1[off] : 0.f;
        sy[r][c] = ok ? p2[off] : 0.f;
    }
    __syncthreads();

    // horizontal separable pass over 5 channels (products formed on the fly)
    for (int i = tid; i < HH * TW; i += BSIZE) {
        int r = i >> 5, c = i & 31;
        float s1 = 0.f, s2 = 0.f, s11 = 0.f, s22 = 0.f, s12 = 0.f;
        #pragma unroll
        for (int k = 0; k < K; ++k) {
            float w = gw[k];
            float a = sx[r][c + k];
            float bb = sy[r][c + k];
            s1  += w * a;
            s2  += w * bb;
            s11 += w * a * a;
            s22 += w * bb * bb;
            s12 += w * a * bb;
        }
        hb1[r][c] = s1; hb2[r][c] = s2;
        hb11[r][c] = s11; hb22[r][c] = s22; hb12[r][c] = s12;
    }
    __syncthreads();

    // vertical pass + SSIM + per-thread accumulate
    const float C1 = 1e-4f;   // 0.01^2
    const float C2 = 9e-4f;   // 0.03^2
    float acc = 0.f;
    for (int i = tid; i < TH * TW; i += BSIZE) {
        int r = i >> 5, c = i & 31;
        float m1 = 0.f, m2 = 0.f, e11 = 0.f, e22 = 0.f, e12 = 0.f;
        #pragma unroll
        for (int k = 0; k < K; ++k) {
            float w = gw[k];
            m1  += w * hb1[r + k][c];
            m2  += w * hb2[r + k][c];
            e11 += w * hb11[r + k][c];
            e22 += w * hb22[r + k][c];
            e12 += w * hb12[r + k][c];
        }
        float mu1s = m1 * m1, mu2s = m2 * m2, mu12 = m1 * m2;
        float sig1 = e11 - mu1s, sig2 = e22 - mu2s, sig12 = e12 - mu12;
        float num = (2.f * mu12 + C1) * (2.f * sig12 + C2);
        float den = (mu1s + mu2s + C1) * (sig1 + sig2 + C2);
        acc += num / den;
    }

    // block reduction: wave64 shuffle then cross-wave via LDS
    for (int d = 32; d > 0; d >>= 1) acc += __shfl_down(acc, d, 64);
    int wid = tid >> 6, lane = tid & 63;
    if (lane == 0) wsum[wid] = acc;
    __syncthreads();
    if (tid == 0) {
        float s = wsum[0] + wsum[1] + wsum[2] + wsum[3];
        int bid = (blockIdx.z * gridDim.y + blockIdx.y) * gridDim.x + blockIdx.x;
        partials[bid] = s;
    }
}

__global__ __launch_bounds__(256) void ssim_reduce_kernel(
    const float* __restrict__ partials, int n, float* __restrict__ out)
{
    __shared__ double wsumd[4];
    double s = 0.0;
    for (int i = threadIdx.x; i < n; i += 256) s += (double)partials[i];
    for (int d = 32; d > 0; d >>= 1) s += __shfl_down(s, d, 64);
    int wid = threadIdx.x >> 6, lane = threadIdx.x & 63;
    if (lane == 0) wsumd[wid] = s;
    __syncthreads();
    if (threadIdx.x == 0) {
        double t = wsumd[0] + wsumd[1] + wsumd[2] + wsumd[3];
        out[0] = (float)(t / ((double)BATCH * IMG_H * IMG_W));
    }
}

extern "C" void kernel_launch(void* const* d_in, const int* in_sizes, int n_in,
                              void* d_out, int out_size, void* d_ws, size_t ws_size,
                              hipStream_t stream) {
    const float* img1   = (const float*)d_in[0];
    const float* img2   = (const float*)d_in[1];
    const float* window = (const float*)d_in[2];
    float* out = (float*)d_out;
    float* partials = (float*)d_ws;

    dim3 grid(IMG_W / TW, IMG_H / TH, BATCH);   // 16 x 16 x 64 = 16384 blocks
    dim3 block(BSIZE);
    ssim_tile_kernel<<<grid, block, 0, stream>>>(img1, img2, window, partials);

    int npart = (IMG_W / TW) * (IMG_H / TH) * BATCH;
    ssim_reduce_kernel<<<1, 256, 0, stream>>>(partials, npart, out);
}

// Round 2
// 126.356 us; speedup vs baseline: 1.7287x; 1.7287x over previous
//
#include <hip/hip_runtime.h>

#define K 11
#define RAD 5
#define TILE 64             // 64x64 output tile per block
#define RROWS (TILE + 2*RAD)        // 74 raw rows
#define RCOLS 80                    // raw cols: tx0-8 .. tx0+71 (float4 aligned)
#define RCHUNKS (RCOLS/4)           // 20 float4 per row
#define BSIZE 256
#define IMG_H 512
#define IMG_W 512
#define BATCH 64

__global__ __launch_bounds__(BSIZE) void ssim_fused_kernel(
    const float* __restrict__ img1, const float* __restrict__ img2,
    const float* __restrict__ window, float* __restrict__ partials)
{
    __shared__ float sA[RROWS][RCOLS];
    __shared__ float sB[RROWS][RCOLS];
    __shared__ float gwS[K];
    __shared__ float wred[4];

    const int tid = threadIdx.x;
    const int b   = blockIdx.z;
    const int ty0 = blockIdx.y * TILE;
    const int tx0 = blockIdx.x * TILE;

    // 1-D gaussian from row sums of the 2-D window (rows sum to g[i] since sum(g)=1)
    if (tid < K) {
        float s = 0.f;
        #pragma unroll
        for (int j = 0; j < K; ++j) s += window[tid*K + j];
        gwS[tid] = s;
    }

    const float* p1 = img1 + (size_t)b * (IMG_H*IMG_W);
    const float* p2 = img2 + (size_t)b * (IMG_H*IMG_W);

    // stage raw tiles (zero-filled halo = SAME zero padding), float4 chunks
    for (int idx = tid; idx < RROWS*RCHUNKS; idx += BSIZE) {
        int r  = idx / RCHUNKS;
        int ch = idx % RCHUNKS;
        int gr = ty0 - RAD + r;
        int gc = tx0 - 8 + ch*4;
        float4 va = {0.f,0.f,0.f,0.f}, vb = {0.f,0.f,0.f,0.f};
        if (gr >= 0 && gr < IMG_H) {
            if (gc >= 0 && gc + 3 < IMG_W) {
                va = *(const float4*)(p1 + (size_t)gr*IMG_W + gc);
                vb = *(const float4*)(p2 + (size_t)gr*IMG_W + gc);
            } else {
                float* pa = (float*)&va; float* pb = (float*)&vb;
                #pragma unroll
                for (int e = 0; e < 4; ++e) {
                    int c = gc + e;
                    if (c >= 0 && c < IMG_W) {
                        pa[e] = p1[(size_t)gr*IMG_W + c];
                        pb[e] = p2[(size_t)gr*IMG_W + c];
                    }
                }
            }
        }
        *(float4*)&sA[r][ch*4] = va;
        *(float4*)&sB[r][ch*4] = vb;
    }
    __syncthreads();

    float g[K];
    #pragma unroll
    for (int k = 0; k < K; ++k) g[k] = gwS[k];

    // thread -> 4x4 output block: cols cx..cx+3, rows ry..ry+3 (local)
    const int cx = (tid & 15) * 4;
    const int ry = (tid >> 4) * 4;

    float m1[4][4], m2[4][4], e11[4][4], e22[4][4], e12[4][4];
    #pragma unroll
    for (int r = 0; r < 4; ++r)
        #pragma unroll
        for (int c = 0; c < 4; ++c) {
            m1[r][c]=0.f; m2[r][c]=0.f; e11[r][c]=0.f; e22[r][c]=0.f; e12[r][c]=0.f;
        }

    // stream 14 h-rows: raw rows ry..ry+13. For each, horizontal conv in regs,
    // then scatter-accumulate into the 4 output-row accumulators.
    #pragma unroll
    for (int j = 0; j < 14; ++j) {
        const int rr = ry + j;
        float a[20], bb[20];
        #pragma unroll
        for (int q = 0; q < 5; ++q) {
            float4 va = *(const float4*)&sA[rr][cx + q*4];
            float4 vb = *(const float4*)&sB[rr][cx + q*4];
            a[q*4+0]=va.x; a[q*4+1]=va.y; a[q*4+2]=va.z; a[q*4+3]=va.w;
            bb[q*4+0]=vb.x; bb[q*4+1]=vb.y; bb[q*4+2]=vb.z; bb[q*4+3]=vb.w;
        }
        float h1[4], h2[4], h11[4], h22[4], h12[4];
        #pragma unroll
        for (int c = 0; c < 4; ++c) { h1[c]=0.f; h2[c]=0.f; h11[c]=0.f; h22[c]=0.f; h12[c]=0.f; }

        // output local col c uses raw indices c+3 .. c+13 (tap k: i = c+3+k)
        #pragma unroll
        for (int i = 3; i <= 16; ++i) {
            float av = a[i], bv = bb[i];
            float a2 = av*av, b2 = bv*bv, ab = av*bv;
            #pragma unroll
            for (int c = 0; c < 4; ++c) {
                const int k = i - 3 - c;
                if (k >= 0 && k <= 10) {
                    float w = g[k];
                    h1[c]  += w*av;  h2[c]  += w*bv;
                    h11[c] += w*a2;  h22[c] += w*b2;  h12[c] += w*ab;
                }
            }
        }

        // vertical: output row r (local) needs h rows j = r + k, k=0..10
        #pragma unroll
        for (int r = 0; r < 4; ++r) {
            const int k = j - r;
            if (k >= 0 && k <= 10) {
                float w = g[k];
                #pragma unroll
                for (int c = 0; c < 4; ++c) {
                    m1[r][c]  += w*h1[c];  m2[r][c]  += w*h2[c];
                    e11[r][c] += w*h11[c]; e22[r][c] += w*h22[c]; e12[r][c] += w*h12[c];
                }
            }
        }
    }

    // SSIM per pixel + thread accumulate
    const float C1 = 1e-4f, C2 = 9e-4f;
    float acc = 0.f;
    #pragma unroll
    for (int r = 0; r < 4; ++r)
        #pragma unroll
        for (int c = 0; c < 4; ++c) {
            float mu1 = m1[r][c], mu2 = m2[r][c];
            float mu1s = mu1*mu1, mu2s = mu2*mu2, mu12 = mu1*mu2;
            float s1 = e11[r][c] - mu1s, s2 = e22[r][c] - mu2s, s12 = e12[r][c] - mu12;
            float num = (2.f*mu12 + C1) * (2.f*s12 + C2);
            float den = (mu1s + mu2s + C1) * (s1 + s2 + C2);
            acc += num / den;
        }

    // block reduction
    for (int d = 32; d > 0; d >>= 1) acc += __shfl_down(acc, d, 64);
    int wid = tid >> 6, lane = tid & 63;
    if (lane == 0) wred[wid] = acc;
    __syncthreads();
    if (tid == 0) {
        float s = wred[0] + wred[1] + wred[2] + wred[3];
        int bid = (blockIdx.z * gridDim.y + blockIdx.y) * gridDim.x + blockIdx.x;
        partials[bid] = s;
    }
}

__global__ __launch_bounds__(256) void ssim_reduce_kernel(
    const float* __restrict__ partials, int n, float* __restrict__ out)
{
    __shared__ double wsumd[4];
    double s = 0.0;
    for (int i = threadIdx.x; i < n; i += 256) s += (double)partials[i];
    for (int d = 32; d > 0; d >>= 1) s += __shfl_down(s, d, 64);
    int wid = threadIdx.x >> 6, lane = threadIdx.x & 63;
    if (lane == 0) wsumd[wid] = s;
    __syncthreads();
    if (threadIdx.x == 0) {
        double t = wsumd[0] + wsumd[1] + wsumd[2] + wsumd[3];
        out[0] = (float)(t / ((double)BATCH * IMG_H * IMG_W));
    }
}

extern "C" void kernel_launch(void* const* d_in, const int* in_sizes, int n_in,
                              void* d_out, int out_size, void* d_ws, size_t ws_size,
                              hipStream_t stream) {
    const float* img1   = (const float*)d_in[0];
    const float* img2   = (const float*)d_in[1];
    const float* window = (const float*)d_in[2];
    float* out = (float*)d_out;
    float* partials = (float*)d_ws;

    dim3 grid(IMG_W / TILE, IMG_H / TILE, BATCH);   // 8 x 8 x 64 = 4096 blocks
    dim3 block(BSIZE);
    ssim_fused_kernel<<<grid, block, 0, stream>>>(img1, img2, window, partials);

    int npart = (IMG_W / TILE) * (IMG_H / TILE) * BATCH;
    ssim_reduce_kernel<<<1, 256, 0, stream>>>(partials, npart, out);
}